// Round 1
// baseline (1048.558 us; speedup 1.0000x reference)
//
#include <hip/hip_runtime.h>
#include <math.h>

#define U_CNT 100000
#define I_CNT 50000
#define D_DIM 64
#define N_CNT 150000
#define B_CNT 8192
#define NEG_SLOPE 0.2f
#define REG_LAMBDA 1e-4f

// ---------------- CSR build ----------------

__global__ void k_hist(const int* __restrict__ rows, int* __restrict__ cnt, int E) {
    int e = blockIdx.x * blockDim.x + threadIdx.x;
    if (e < E) atomicAdd(&cnt[rows[e]], 1);
}

// inclusive scan of cnt[0..n-1] written to rs[1..n]; per-block totals to bsum
__global__ void k_scan1(const int* __restrict__ cnt, int* __restrict__ rs,
                        int* __restrict__ bsum, int n) {
    __shared__ int lds[256];
    int tid = threadIdx.x;
    int base = blockIdx.x * 2048 + tid * 8;
    int v[8];
    int run = 0;
#pragma unroll
    for (int i = 0; i < 8; ++i) {
        int x = (base + i < n) ? cnt[base + i] : 0;
        run += x;
        v[i] = run;
    }
    lds[tid] = run;
    __syncthreads();
    for (int off = 1; off < 256; off <<= 1) {
        int t = (tid >= off) ? lds[tid - off] : 0;
        __syncthreads();
        lds[tid] += t;
        __syncthreads();
    }
    int excl = lds[tid] - run;
#pragma unroll
    for (int i = 0; i < 8; ++i) {
        if (base + i < n) rs[base + i + 1] = excl + v[i];
    }
    if (tid == 255) bsum[blockIdx.x] = lds[255];
}

// exclusive scan of bsum (nb <= 256), also writes rs[0]=0
__global__ void k_scan2(int* __restrict__ bsum, int nb, int* __restrict__ rs) {
    __shared__ int lds[256];
    int tid = threadIdx.x;
    int x = (tid < nb) ? bsum[tid] : 0;
    lds[tid] = x;
    __syncthreads();
    for (int off = 1; off < 256; off <<= 1) {
        int t = (tid >= off) ? lds[tid - off] : 0;
        __syncthreads();
        lds[tid] += t;
        __syncthreads();
    }
    if (tid < nb) bsum[tid] = lds[tid] - x;
    if (tid == 0) rs[0] = 0;
}

__global__ void k_scan3(int* __restrict__ rs, const int* __restrict__ bsum, int n) {
    int add = bsum[blockIdx.x];
    int base = blockIdx.x * 2048 + threadIdx.x * 8;
#pragma unroll
    for (int i = 0; i < 8; ++i) {
        if (base + i < n) rs[base + i + 1] += add;
    }
}

__global__ void k_scatter(const int* __restrict__ rows, const int* __restrict__ cols,
                          const float* __restrict__ vals, const int* __restrict__ rs,
                          int* __restrict__ fill, int* __restrict__ cols_s,
                          float* __restrict__ vals_s, int E) {
    int e = blockIdx.x * blockDim.x + threadIdx.x;
    if (e >= E) return;
    int r = rows[e];
    int pos = atomicAdd(&fill[r], 1);
    int slot = rs[r] + pos;
    cols_s[slot] = cols[e];
    vals_s[slot] = vals[e];
}

// ---------------- SPMM: one wave per row, lane = dim ----------------
// src row c: c < split -> srcA + c*64 ; else srcB + (c-split)*64
__global__ void k_spmm(const int* __restrict__ rs, const int* __restrict__ cols_s,
                       const float* __restrict__ vals_s,
                       const float* __restrict__ srcA, const float* __restrict__ srcB,
                       int split, float* __restrict__ out) {
    int gid = blockIdx.x * blockDim.x + threadIdx.x;
    int w = gid >> 6;
    int lane = gid & 63;
    if (w >= N_CNT) return;
    int s = rs[w], e = rs[w + 1];
    float acc = 0.f;
    int i = s;
    for (; i + 4 <= e; i += 4) {
        int c0 = cols_s[i], c1 = cols_s[i + 1], c2 = cols_s[i + 2], c3 = cols_s[i + 3];
        float v0 = vals_s[i], v1 = vals_s[i + 1], v2 = vals_s[i + 2], v3 = vals_s[i + 3];
        const float* p0 = (c0 < split) ? srcA + (size_t)c0 * 64 : srcB + (size_t)(c0 - split) * 64;
        const float* p1 = (c1 < split) ? srcA + (size_t)c1 * 64 : srcB + (size_t)(c1 - split) * 64;
        const float* p2 = (c2 < split) ? srcA + (size_t)c2 * 64 : srcB + (size_t)(c2 - split) * 64;
        const float* p3 = (c3 < split) ? srcA + (size_t)c3 * 64 : srcB + (size_t)(c3 - split) * 64;
        float a0 = p0[lane], a1 = p1[lane], a2 = p2[lane], a3 = p3[lane];
        acc = fmaf(v0, a0, acc);
        acc = fmaf(v1, a1, acc);
        acc = fmaf(v2, a2, acc);
        acc = fmaf(v3, a3, acc);
    }
    for (; i < e; ++i) {
        int c = cols_s[i];
        float v = vals_s[i];
        const float* p = (c < split) ? srcA + (size_t)c * 64 : srcB + (size_t)(c - split) * 64;
        acc = fmaf(v, p[lane], acc);
    }
    out[(size_t)w * 64 + lane] = acc;
}

// ---------------- fused dense: leaky_relu(x@Wg+bg)@Wm+bm, row norm ----------------
__global__ __launch_bounds__(256, 1) void k_dense(const float* __restrict__ x_in,
                                                  const float* __restrict__ Wg,
                                                  const float* __restrict__ bg,
                                                  const float* __restrict__ Wm,
                                                  const float* __restrict__ bm,
                                                  float* __restrict__ out,
                                                  float* __restrict__ rnorm) {
    __shared__ __align__(16) float sWgT[4096];  // transposed: [j][k]
    __shared__ __align__(16) float sWm[4096];   // row-major:  [j][j2]
    __shared__ float sbg[64], sbm[64];
    int tid = threadIdx.x;
    for (int i = tid; i < 4096; i += 256) {
        int k = i >> 6, j = i & 63;
        sWgT[j * 64 + k] = Wg[i];
        sWm[i] = Wm[i];
    }
    if (tid < 64) {
        sbg[tid] = bg[tid];
        sbm[tid] = bm[tid];
    }
    __syncthreads();
    int r = blockIdx.x * 256 + tid;
    if (r >= N_CNT) return;

    float4 x4[16];
    const float4* xp = (const float4*)(x_in + (size_t)r * 64);
#pragma unroll
    for (int i = 0; i < 16; ++i) x4[i] = xp[i];

    float z[64];
#pragma unroll
    for (int j = 0; j < 64; ++j) z[j] = sbm[j];

    for (int j = 0; j < 64; ++j) {
        float acc = sbg[j];
#pragma unroll
        for (int k = 0; k < 16; ++k) {
            float4 w = *(const float4*)&sWgT[j * 64 + k * 4];
            acc = fmaf(x4[k].x, w.x, acc);
            acc = fmaf(x4[k].y, w.y, acc);
            acc = fmaf(x4[k].z, w.z, acc);
            acc = fmaf(x4[k].w, w.w, acc);
        }
        float y = (acc >= 0.f) ? acc : NEG_SLOPE * acc;
#pragma unroll
        for (int k = 0; k < 16; ++k) {
            float4 w = *(const float4*)&sWm[j * 64 + k * 4];
            z[k * 4 + 0] = fmaf(y, w.x, z[k * 4 + 0]);
            z[k * 4 + 1] = fmaf(y, w.y, z[k * 4 + 1]);
            z[k * 4 + 2] = fmaf(y, w.z, z[k * 4 + 2]);
            z[k * 4 + 3] = fmaf(y, w.w, z[k * 4 + 3]);
        }
    }
    float nrm2 = 0.f;
#pragma unroll
    for (int j = 0; j < 64; ++j) nrm2 = fmaf(z[j], z[j], nrm2);
    float nrm = sqrtf(nrm2);
    float rn = 1.f / fmaxf(nrm, 1e-12f);
    rnorm[r] = rn;
    float4* op = (float4*)(out + (size_t)r * 64);
#pragma unroll
    for (int i = 0; i < 16; ++i) {
        float4 t;
        t.x = z[i * 4 + 0];
        t.y = z[i * 4 + 1];
        t.z = z[i * 4 + 2];
        t.w = z[i * 4 + 3];
        op[i] = t;
    }
}

// ---------------- BPR scoring: one wave per sample ----------------
__global__ void k_score(const int* __restrict__ user, const int* __restrict__ posi,
                        const int* __restrict__ negi,
                        const float* __restrict__ uemb, const float* __restrict__ iemb,
                        const float* __restrict__ ego1, const float* __restrict__ rn1,
                        const float* __restrict__ ego2, const float* __restrict__ rn2,
                        float* __restrict__ out) {
    int gid = blockIdx.x * blockDim.x + threadIdx.x;
    int w = gid >> 6;
    int lane = gid & 63;
    if (w >= B_CNT) return;
    int iu = user[w], ip = posi[w], ineg = negi[w];
    size_t ru = (size_t)iu;
    size_t rp = (size_t)U_CNT + ip;
    size_t rn_ = (size_t)U_CNT + ineg;

    float u0 = uemb[(size_t)iu * 64 + lane];
    float p0 = iemb[(size_t)ip * 64 + lane];
    float n0 = iemb[(size_t)ineg * 64 + lane];
    float pos = u0 * p0;
    float neg = u0 * n0;
    float reg = u0 * u0 + p0 * p0 + n0 * n0;

    float a1 = rn1[ru], b1 = rn1[rp], c1 = rn1[rn_];
    float u1 = ego1[ru * 64 + lane] * a1;
    float p1 = ego1[rp * 64 + lane] * b1;
    float n1 = ego1[rn_ * 64 + lane] * c1;
    pos = fmaf(u1, p1, pos);
    neg = fmaf(u1, n1, neg);

    float a2 = rn2[ru], b2 = rn2[rp], c2 = rn2[rn_];
    float u2 = ego2[ru * 64 + lane] * a2;
    float p2 = ego2[rp * 64 + lane] * b2;
    float n2 = ego2[rn_ * 64 + lane] * c2;
    pos = fmaf(u2, p2, pos);
    neg = fmaf(u2, n2, neg);

#pragma unroll
    for (int off = 32; off; off >>= 1) {
        pos += __shfl_xor(pos, off);
        neg += __shfl_xor(neg, off);
        reg += __shfl_xor(reg, off);
    }
    if (lane == 0) {
        float t = neg - pos;
        float sp = fmaxf(t, 0.f) + log1pf(expf(-fabsf(t)));
        atomicAdd(&out[0], sp * (1.0f / B_CNT));
        atomicAdd(&out[1], reg * (0.5f * REG_LAMBDA / B_CNT));
    }
}

// ---------------- launch ----------------

static inline size_t alignup(size_t x) { return (x + 255) & ~(size_t)255; }

extern "C" void kernel_launch(void* const* d_in, const int* in_sizes, int n_in,
                              void* d_out, int out_size, void* d_ws, size_t ws_size,
                              hipStream_t stream) {
    const int* user = (const int*)d_in[0];
    const int* posi = (const int*)d_in[1];
    const int* negi = (const int*)d_in[2];
    const int* rows = (const int*)d_in[3];
    const int* cols = (const int*)d_in[4];
    const float* vals = (const float*)d_in[5];
    const float* uemb = (const float*)d_in[6];
    const float* iemb = (const float*)d_in[7];
    const float* Wg0 = (const float*)d_in[8];
    const float* bg0 = (const float*)d_in[9];
    const float* Wm0 = (const float*)d_in[10];
    const float* bm0 = (const float*)d_in[11];
    const float* Wg1 = (const float*)d_in[12];
    const float* bg1 = (const float*)d_in[13];
    const float* Wm1 = (const float*)d_in[14];
    const float* bm1 = (const float*)d_in[15];
    const int E = in_sizes[3];
    float* out = (float*)d_out;

    char* p = (char*)d_ws;
    auto take = [&](size_t bytes) -> char* {
        char* q = p;
        p += alignup(bytes);
        return q;
    };
    int* rs = (int*)take((size_t)(N_CNT + 1) * 4);
    int* fill = (int*)take((size_t)N_CNT * 4);
    int* bsum = (int*)take(4096);
    int* cols_s = (int*)take((size_t)E * 4);
    float* vals_s = (float*)take((size_t)E * 4);
    float* side = (float*)take((size_t)N_CNT * 64 * 4);
    float* ego1 = (float*)take((size_t)N_CNT * 64 * 4);
    float* ego2 = (float*)take((size_t)N_CNT * 64 * 4);
    float* rn1 = (float*)take((size_t)N_CNT * 4);
    float* rn2 = (float*)take((size_t)N_CNT * 4);

    hipMemsetAsync(out, 0, 2 * sizeof(float), stream);
    hipMemsetAsync(fill, 0, (size_t)N_CNT * 4, stream);

    int eb = (E + 255) / 256;
    k_hist<<<eb, 256, 0, stream>>>(rows, fill, E);

    int nb = (N_CNT + 2047) / 2048;
    k_scan1<<<nb, 256, 0, stream>>>(fill, rs, bsum, N_CNT);
    k_scan2<<<1, 256, 0, stream>>>(bsum, nb, rs);
    k_scan3<<<nb, 256, 0, stream>>>(rs, bsum, N_CNT);

    hipMemsetAsync(fill, 0, (size_t)N_CNT * 4, stream);
    k_scatter<<<eb, 256, 0, stream>>>(rows, cols, vals, rs, fill, cols_s, vals_s, E);

    int sb = (N_CNT * 64 + 255) / 256;
    int db = (N_CNT + 255) / 256;

    k_spmm<<<sb, 256, 0, stream>>>(rs, cols_s, vals_s, uemb, iemb, U_CNT, side);
    k_dense<<<db, 256, 0, stream>>>(side, Wg0, bg0, Wm0, bm0, ego1, rn1);
    k_spmm<<<sb, 256, 0, stream>>>(rs, cols_s, vals_s, ego1, ego1, N_CNT, side);
    k_dense<<<db, 256, 0, stream>>>(side, Wg1, bg1, Wm1, bm1, ego2, rn2);

    k_score<<<(B_CNT * 64) / 256, 256, 0, stream>>>(user, posi, negi, uemb, iemb,
                                                    ego1, rn1, ego2, rn2, out);
}

// Round 2
// 849.361 us; speedup vs baseline: 1.2345x; 1.2345x over previous
//
#include <hip/hip_runtime.h>
#include <math.h>

#define U_CNT 100000
#define I_CNT 50000
#define D_DIM 64
#define N_CNT 150000
#define B_CNT 8192
#define NEG_SLOPE 0.2f
#define REG_LAMBDA 1e-4f

#define RPB 128                      // rows per bucket
#define NBK ((N_CNT + RPB - 1) / RPB)  // 1172 buckets
#define CAP 4096                     // LDS edge capacity per bucket (mean ~2560, sigma ~51)

// ---------------- bucketed CSR build ----------------

// Stage 0: per-bucket histogram, block-aggregated in LDS.
__global__ __launch_bounds__(256) void k_bhist(const int* __restrict__ rows,
                                               int* __restrict__ bcnt, int E) {
    __shared__ int h[NBK];
    for (int i = threadIdx.x; i < NBK; i += 256) h[i] = 0;
    __syncthreads();
    int per = (E + gridDim.x - 1) / gridDim.x;
    int s = blockIdx.x * per, e = min(E, s + per);
    for (int i = s + threadIdx.x; i < e; i += 256) atomicAdd(&h[rows[i] >> 7], 1);
    __syncthreads();
    for (int i = threadIdx.x; i < NBK; i += 256) {
        int v = h[i];
        if (v) atomicAdd(&bcnt[i], v);
    }
}

// Stage 1: exclusive scan of bucket counts -> bb[0..NBK], single block.
__global__ void k_bscan(const int* __restrict__ bcnt, int* __restrict__ bb, int n) {
    __shared__ int lds[256];
    __shared__ int base;
    int tid = threadIdx.x;
    if (tid == 0) { base = 0; bb[0] = 0; }
    __syncthreads();
    for (int start = 0; start < n; start += 256) {
        int i = start + tid;
        int x = (i < n) ? bcnt[i] : 0;
        lds[tid] = x;
        __syncthreads();
        for (int off = 1; off < 256; off <<= 1) {
            int t = (tid >= off) ? lds[tid - off] : 0;
            __syncthreads();
            lds[tid] += t;
            __syncthreads();
        }
        if (i < n) bb[i + 1] = base + lds[tid];
        __syncthreads();
        if (tid == 0) base += lds[255];
        __syncthreads();
    }
}

// Stage 2: scatter edges to bucket-contiguous regions. Block-aggregated
// reservations make each block's writes per bucket a contiguous run.
// Packed edge: x = (row_local<<18) | col  (col < 2^18), y = bits(val).
__global__ __launch_bounds__(256) void k_bscatterA(const int* __restrict__ rows,
                                                   const int* __restrict__ cols,
                                                   const float* __restrict__ vals,
                                                   const int* __restrict__ bb,
                                                   int* __restrict__ bfill,
                                                   int2* __restrict__ edges, int E) {
    __shared__ int h[NBK];  // pass1: count, then block base within bucket
    __shared__ int f[NBK];  // pass2 fill
    for (int i = threadIdx.x; i < NBK; i += 256) { h[i] = 0; f[i] = 0; }
    __syncthreads();
    int per = (E + gridDim.x - 1) / gridDim.x;
    int s = blockIdx.x * per, e = min(E, s + per);
    for (int i = s + threadIdx.x; i < e; i += 256) atomicAdd(&h[rows[i] >> 7], 1);
    __syncthreads();
    for (int i = threadIdx.x; i < NBK; i += 256) {
        int c = h[i];
        h[i] = c ? atomicAdd(&bfill[i], c) : 0;
    }
    __syncthreads();
    for (int i = s + threadIdx.x; i < e; i += 256) {
        int r = rows[i];
        int b = r >> 7, rl = r & 127;
        int pos = atomicAdd(&f[b], 1);
        int slot = bb[b] + h[b] + pos;
        edges[slot] = make_int2((rl << 18) | cols[i], __float_as_int(vals[i]));
    }
}

// Stage 3: one block per bucket — exact CSR order within the bucket, in LDS,
// writes rs[] and the cleaned {col,val} edges back in place, coalesced.
__global__ __launch_bounds__(256) void k_bfinal(int2* __restrict__ edges,
                                                const int* __restrict__ bb,
                                                int* __restrict__ rs, int E) {
    __shared__ int2 led[CAP];
    __shared__ int lcnt[RPB], lscan[RPB], lfill[RPB];
    int b = blockIdx.x;
    int s = bb[b], e = bb[b + 1];
    int nb = e - s;
    int tid = threadIdx.x;
    if (tid < RPB) { lcnt[tid] = 0; lfill[tid] = 0; }
    __syncthreads();
    for (int i = tid; i < nb; i += 256) {
        int2 ed = edges[s + i];
        if (i < CAP) led[i] = ed;
        atomicAdd(&lcnt[ed.x >> 18], 1);
    }
    __syncthreads();
    if (tid == 0) {
        int run = 0;
        for (int j = 0; j < RPB; ++j) { lscan[j] = run; run += lcnt[j]; }
    }
    __syncthreads();
    if (tid < RPB) {
        int row = b * RPB + tid;
        if (row < N_CNT) rs[row] = s + lscan[tid];
    }
    if (b == gridDim.x - 1 && tid == 0) rs[N_CNT] = E;
    int lim = min(nb, CAP);
    for (int i = tid; i < lim; i += 256) {
        int2 ed = led[i];
        int rl = ed.x >> 18;
        int pos = atomicAdd(&lfill[rl], 1);
        edges[s + lscan[rl] + pos] = make_int2(ed.x & 0x3FFFF, ed.y);
    }
    // overflow path (statistically unreachable: bucket mean 2560, CAP 4096)
    for (int base = CAP; base < nb; base += 256) {
        int i = base + tid;
        int2 ed;
        bool ok = (i < nb);
        if (ok) ed = edges[s + i];
        __syncthreads();
        if (ok) {
            int rl = ed.x >> 18;
            int pos = atomicAdd(&lfill[rl], 1);
            edges[s + lscan[rl] + pos] = make_int2(ed.x & 0x3FFFF, ed.y);
        }
        __syncthreads();
    }
}

// ---------------- SPMM: one wave per row, lane = dim ----------------
__global__ void k_spmm(const int* __restrict__ rs, const int2* __restrict__ edges,
                       const float* __restrict__ srcA, const float* __restrict__ srcB,
                       int split, float* __restrict__ out) {
    int gid = blockIdx.x * blockDim.x + threadIdx.x;
    int w = gid >> 6;
    int lane = gid & 63;
    if (w >= N_CNT) return;
    int s = rs[w], e = rs[w + 1];
    float acc = 0.f;
    int i = s;
    for (; i + 4 <= e; i += 4) {
        int2 e0 = edges[i], e1 = edges[i + 1], e2 = edges[i + 2], e3 = edges[i + 3];
        const float* p0 = (e0.x < split) ? srcA + (size_t)e0.x * 64 : srcB + (size_t)(e0.x - split) * 64;
        const float* p1 = (e1.x < split) ? srcA + (size_t)e1.x * 64 : srcB + (size_t)(e1.x - split) * 64;
        const float* p2 = (e2.x < split) ? srcA + (size_t)e2.x * 64 : srcB + (size_t)(e2.x - split) * 64;
        const float* p3 = (e3.x < split) ? srcA + (size_t)e3.x * 64 : srcB + (size_t)(e3.x - split) * 64;
        float a0 = p0[lane], a1 = p1[lane], a2 = p2[lane], a3 = p3[lane];
        acc = fmaf(__int_as_float(e0.y), a0, acc);
        acc = fmaf(__int_as_float(e1.y), a1, acc);
        acc = fmaf(__int_as_float(e2.y), a2, acc);
        acc = fmaf(__int_as_float(e3.y), a3, acc);
    }
    for (; i < e; ++i) {
        int2 ed = edges[i];
        const float* p = (ed.x < split) ? srcA + (size_t)ed.x * 64 : srcB + (size_t)(ed.x - split) * 64;
        acc = fmaf(__int_as_float(ed.y), p[lane], acc);
    }
    out[(size_t)w * 64 + lane] = acc;
}

// ---------------- fused dense: leaky_relu(x@Wg+bg)@Wm+bm, row norm ----------------
__global__ __launch_bounds__(256, 1) void k_dense(const float* __restrict__ x_in,
                                                  const float* __restrict__ Wg,
                                                  const float* __restrict__ bg,
                                                  const float* __restrict__ Wm,
                                                  const float* __restrict__ bm,
                                                  float* __restrict__ out,
                                                  float* __restrict__ rnorm) {
    __shared__ __align__(16) float sWgT[4096];  // transposed: [j][k]
    __shared__ __align__(16) float sWm[4096];   // row-major:  [j][j2]
    __shared__ float sbg[64], sbm[64];
    int tid = threadIdx.x;
    for (int i = tid; i < 4096; i += 256) {
        int k = i >> 6, j = i & 63;
        sWgT[j * 64 + k] = Wg[i];
        sWm[i] = Wm[i];
    }
    if (tid < 64) {
        sbg[tid] = bg[tid];
        sbm[tid] = bm[tid];
    }
    __syncthreads();
    int r = blockIdx.x * 256 + tid;
    if (r >= N_CNT) return;

    float4 x4[16];
    const float4* xp = (const float4*)(x_in + (size_t)r * 64);
#pragma unroll
    for (int i = 0; i < 16; ++i) x4[i] = xp[i];

    float z[64];
#pragma unroll
    for (int j = 0; j < 64; ++j) z[j] = sbm[j];

    for (int j = 0; j < 64; ++j) {
        float acc = sbg[j];
#pragma unroll
        for (int k = 0; k < 16; ++k) {
            float4 w = *(const float4*)&sWgT[j * 64 + k * 4];
            acc = fmaf(x4[k].x, w.x, acc);
            acc = fmaf(x4[k].y, w.y, acc);
            acc = fmaf(x4[k].z, w.z, acc);
            acc = fmaf(x4[k].w, w.w, acc);
        }
        float y = (acc >= 0.f) ? acc : NEG_SLOPE * acc;
#pragma unroll
        for (int k = 0; k < 16; ++k) {
            float4 w = *(const float4*)&sWm[j * 64 + k * 4];
            z[k * 4 + 0] = fmaf(y, w.x, z[k * 4 + 0]);
            z[k * 4 + 1] = fmaf(y, w.y, z[k * 4 + 1]);
            z[k * 4 + 2] = fmaf(y, w.z, z[k * 4 + 2]);
            z[k * 4 + 3] = fmaf(y, w.w, z[k * 4 + 3]);
        }
    }
    float nrm2 = 0.f;
#pragma unroll
    for (int j = 0; j < 64; ++j) nrm2 = fmaf(z[j], z[j], nrm2);
    float nrm = sqrtf(nrm2);
    float rn = 1.f / fmaxf(nrm, 1e-12f);
    rnorm[r] = rn;
    float4* op = (float4*)(out + (size_t)r * 64);
#pragma unroll
    for (int i = 0; i < 16; ++i) {
        float4 t;
        t.x = z[i * 4 + 0];
        t.y = z[i * 4 + 1];
        t.z = z[i * 4 + 2];
        t.w = z[i * 4 + 3];
        op[i] = t;
    }
}

// ---------------- BPR scoring: one wave per sample ----------------
__global__ void k_score(const int* __restrict__ user, const int* __restrict__ posi,
                        const int* __restrict__ negi,
                        const float* __restrict__ uemb, const float* __restrict__ iemb,
                        const float* __restrict__ ego1, const float* __restrict__ rn1,
                        const float* __restrict__ ego2, const float* __restrict__ rn2,
                        float* __restrict__ out) {
    int gid = blockIdx.x * blockDim.x + threadIdx.x;
    int w = gid >> 6;
    int lane = gid & 63;
    if (w >= B_CNT) return;
    int iu = user[w], ip = posi[w], ineg = negi[w];
    size_t ru = (size_t)iu;
    size_t rp = (size_t)U_CNT + ip;
    size_t rn_ = (size_t)U_CNT + ineg;

    float u0 = uemb[(size_t)iu * 64 + lane];
    float p0 = iemb[(size_t)ip * 64 + lane];
    float n0 = iemb[(size_t)ineg * 64 + lane];
    float pos = u0 * p0;
    float neg = u0 * n0;
    float reg = u0 * u0 + p0 * p0 + n0 * n0;

    float a1 = rn1[ru], b1 = rn1[rp], c1 = rn1[rn_];
    float u1 = ego1[ru * 64 + lane] * a1;
    float p1 = ego1[rp * 64 + lane] * b1;
    float n1 = ego1[rn_ * 64 + lane] * c1;
    pos = fmaf(u1, p1, pos);
    neg = fmaf(u1, n1, neg);

    float a2 = rn2[ru], b2 = rn2[rp], c2 = rn2[rn_];
    float u2 = ego2[ru * 64 + lane] * a2;
    float p2 = ego2[rp * 64 + lane] * b2;
    float n2 = ego2[rn_ * 64 + lane] * c2;
    pos = fmaf(u2, p2, pos);
    neg = fmaf(u2, n2, neg);

#pragma unroll
    for (int off = 32; off; off >>= 1) {
        pos += __shfl_xor(pos, off);
        neg += __shfl_xor(neg, off);
        reg += __shfl_xor(reg, off);
    }
    if (lane == 0) {
        float t = neg - pos;
        float sp = fmaxf(t, 0.f) + log1pf(expf(-fabsf(t)));
        atomicAdd(&out[0], sp * (1.0f / B_CNT));
        atomicAdd(&out[1], reg * (0.5f * REG_LAMBDA / B_CNT));
    }
}

// ---------------- launch ----------------

static inline size_t alignup(size_t x) { return (x + 255) & ~(size_t)255; }

extern "C" void kernel_launch(void* const* d_in, const int* in_sizes, int n_in,
                              void* d_out, int out_size, void* d_ws, size_t ws_size,
                              hipStream_t stream) {
    const int* user = (const int*)d_in[0];
    const int* posi = (const int*)d_in[1];
    const int* negi = (const int*)d_in[2];
    const int* rows = (const int*)d_in[3];
    const int* cols = (const int*)d_in[4];
    const float* vals = (const float*)d_in[5];
    const float* uemb = (const float*)d_in[6];
    const float* iemb = (const float*)d_in[7];
    const float* Wg0 = (const float*)d_in[8];
    const float* bg0 = (const float*)d_in[9];
    const float* Wm0 = (const float*)d_in[10];
    const float* bm0 = (const float*)d_in[11];
    const float* Wg1 = (const float*)d_in[12];
    const float* bg1 = (const float*)d_in[13];
    const float* Wm1 = (const float*)d_in[14];
    const float* bm1 = (const float*)d_in[15];
    const int E = in_sizes[3];
    float* out = (float*)d_out;

    char* p = (char*)d_ws;
    auto take = [&](size_t bytes) -> char* {
        char* q = p;
        p += alignup(bytes);
        return q;
    };
    int* rs = (int*)take((size_t)(N_CNT + 1) * 4);
    int* bcnt = (int*)take((size_t)NBK * 4 * 2);  // bcnt + bfill contiguous
    int* bfill = bcnt + NBK;
    int* bb = (int*)take((size_t)(NBK + 1) * 4);
    int2* edges = (int2*)take((size_t)E * 8);
    float* side = (float*)take((size_t)N_CNT * 64 * 4);
    float* ego1 = (float*)take((size_t)N_CNT * 64 * 4);
    float* ego2 = (float*)take((size_t)N_CNT * 64 * 4);
    float* rn1 = (float*)take((size_t)N_CNT * 4);
    float* rn2 = (float*)take((size_t)N_CNT * 4);

    hipMemsetAsync(out, 0, 2 * sizeof(float), stream);
    hipMemsetAsync(bcnt, 0, (size_t)NBK * 4 * 2, stream);

    k_bhist<<<256, 256, 0, stream>>>(rows, bcnt, E);
    k_bscan<<<1, 256, 0, stream>>>(bcnt, bb, NBK);
    k_bscatterA<<<256, 256, 0, stream>>>(rows, cols, vals, bb, bfill, edges, E);
    k_bfinal<<<NBK, 256, 0, stream>>>(edges, bb, rs, E);

    int sb = (N_CNT * 64 + 255) / 256;
    int db = (N_CNT + 255) / 256;

    k_spmm<<<sb, 256, 0, stream>>>(rs, edges, uemb, iemb, U_CNT, side);
    k_dense<<<db, 256, 0, stream>>>(side, Wg0, bg0, Wm0, bm0, ego1, rn1);
    k_spmm<<<sb, 256, 0, stream>>>(rs, edges, ego1, ego1, N_CNT, side);
    k_dense<<<db, 256, 0, stream>>>(side, Wg1, bg1, Wm1, bm1, ego2, rn2);

    k_score<<<(B_CNT * 64) / 256, 256, 0, stream>>>(user, posi, negi, uemb, iemb,
                                                    ego1, rn1, ego2, rn2, out);
}

// Round 3
// 664.377 us; speedup vs baseline: 1.5783x; 1.2784x over previous
//
#include <hip/hip_runtime.h>
#include <math.h>

#define U_CNT 100000
#define I_CNT 50000
#define D_DIM 64
#define N_CNT 150000
#define B_CNT 8192
#define NEG_SLOPE 0.2f
#define REG_LAMBDA 1e-4f

#define RPB 128                      // rows per bucket
#define NBK ((N_CNT + RPB - 1) / RPB)  // 1172 buckets
#define CAP 4096                     // LDS edge capacity per bucket (mean ~2560, sigma ~51)

// ---------------- bucketed CSR build ----------------

__global__ __launch_bounds__(256) void k_bhist(const int* __restrict__ rows,
                                               int* __restrict__ bcnt, int E) {
    __shared__ int h[NBK];
    for (int i = threadIdx.x; i < NBK; i += 256) h[i] = 0;
    __syncthreads();
    int per = (E + gridDim.x - 1) / gridDim.x;
    int s = blockIdx.x * per, e = min(E, s + per);
    for (int i = s + threadIdx.x; i < e; i += 256) atomicAdd(&h[rows[i] >> 7], 1);
    __syncthreads();
    for (int i = threadIdx.x; i < NBK; i += 256) {
        int v = h[i];
        if (v) atomicAdd(&bcnt[i], v);
    }
}

__global__ void k_bscan(const int* __restrict__ bcnt, int* __restrict__ bb, int n) {
    __shared__ int lds[256];
    __shared__ int base;
    int tid = threadIdx.x;
    if (tid == 0) { base = 0; bb[0] = 0; }
    __syncthreads();
    for (int start = 0; start < n; start += 256) {
        int i = start + tid;
        int x = (i < n) ? bcnt[i] : 0;
        lds[tid] = x;
        __syncthreads();
        for (int off = 1; off < 256; off <<= 1) {
            int t = (tid >= off) ? lds[tid - off] : 0;
            __syncthreads();
            lds[tid] += t;
            __syncthreads();
        }
        if (i < n) bb[i + 1] = base + lds[tid];
        __syncthreads();
        if (tid == 0) base += lds[255];
        __syncthreads();
    }
}

__global__ __launch_bounds__(256) void k_bscatterA(const int* __restrict__ rows,
                                                   const int* __restrict__ cols,
                                                   const float* __restrict__ vals,
                                                   const int* __restrict__ bb,
                                                   int* __restrict__ bfill,
                                                   int2* __restrict__ edges, int E) {
    __shared__ int h[NBK];
    __shared__ int f[NBK];
    for (int i = threadIdx.x; i < NBK; i += 256) { h[i] = 0; f[i] = 0; }
    __syncthreads();
    int per = (E + gridDim.x - 1) / gridDim.x;
    int s = blockIdx.x * per, e = min(E, s + per);
    for (int i = s + threadIdx.x; i < e; i += 256) atomicAdd(&h[rows[i] >> 7], 1);
    __syncthreads();
    for (int i = threadIdx.x; i < NBK; i += 256) {
        int c = h[i];
        h[i] = c ? atomicAdd(&bfill[i], c) : 0;
    }
    __syncthreads();
    for (int i = s + threadIdx.x; i < e; i += 256) {
        int r = rows[i];
        int b = r >> 7, rl = r & 127;
        int pos = atomicAdd(&f[b], 1);
        int slot = bb[b] + h[b] + pos;
        edges[slot] = make_int2((rl << 18) | cols[i], __float_as_int(vals[i]));
    }
}

__global__ __launch_bounds__(256) void k_bfinal(int2* __restrict__ edges,
                                                const int* __restrict__ bb,
                                                int* __restrict__ rs, int E) {
    __shared__ int2 led[CAP];
    __shared__ int lcnt[RPB], lscan[RPB], lfill[RPB];
    int b = blockIdx.x;
    int s = bb[b], e = bb[b + 1];
    int nb = e - s;
    int tid = threadIdx.x;
    if (tid < RPB) { lcnt[tid] = 0; lfill[tid] = 0; }
    __syncthreads();
    for (int i = tid; i < nb; i += 256) {
        int2 ed = edges[s + i];
        if (i < CAP) led[i] = ed;
        atomicAdd(&lcnt[ed.x >> 18], 1);
    }
    __syncthreads();
    if (tid == 0) {
        int run = 0;
        for (int j = 0; j < RPB; ++j) { lscan[j] = run; run += lcnt[j]; }
    }
    __syncthreads();
    if (tid < RPB) {
        int row = b * RPB + tid;
        if (row < N_CNT) rs[row] = s + lscan[tid];
    }
    if (b == gridDim.x - 1 && tid == 0) rs[N_CNT] = E;
    int lim = min(nb, CAP);
    for (int i = tid; i < lim; i += 256) {
        int2 ed = led[i];
        int rl = ed.x >> 18;
        int pos = atomicAdd(&lfill[rl], 1);
        edges[s + lscan[rl] + pos] = make_int2(ed.x & 0x3FFFF, ed.y);
    }
    for (int base = CAP; base < nb; base += 256) {
        int i = base + tid;
        int2 ed;
        bool ok = (i < nb);
        if (ok) ed = edges[s + i];
        __syncthreads();
        if (ok) {
            int rl = ed.x >> 18;
            int pos = atomicAdd(&lfill[rl], 1);
            edges[s + lscan[rl] + pos] = make_int2(ed.x & 0x3FFFF, ed.y);
        }
        __syncthreads();
    }
}

// ---------------- SPMM: one wave per row, lane = dim ----------------
__global__ void k_spmm(const int* __restrict__ rs, const int2* __restrict__ edges,
                       const float* __restrict__ srcA, const float* __restrict__ srcB,
                       int split, float* __restrict__ out) {
    int gid = blockIdx.x * blockDim.x + threadIdx.x;
    int w = gid >> 6;
    int lane = gid & 63;
    if (w >= N_CNT) return;
    int s = rs[w], e = rs[w + 1];
    float acc = 0.f;
    int i = s;
    for (; i + 4 <= e; i += 4) {
        int2 e0 = edges[i], e1 = edges[i + 1], e2 = edges[i + 2], e3 = edges[i + 3];
        const float* p0 = (e0.x < split) ? srcA + (size_t)e0.x * 64 : srcB + (size_t)(e0.x - split) * 64;
        const float* p1 = (e1.x < split) ? srcA + (size_t)e1.x * 64 : srcB + (size_t)(e1.x - split) * 64;
        const float* p2 = (e2.x < split) ? srcA + (size_t)e2.x * 64 : srcB + (size_t)(e2.x - split) * 64;
        const float* p3 = (e3.x < split) ? srcA + (size_t)e3.x * 64 : srcB + (size_t)(e3.x - split) * 64;
        float a0 = p0[lane], a1 = p1[lane], a2 = p2[lane], a3 = p3[lane];
        acc = fmaf(__int_as_float(e0.y), a0, acc);
        acc = fmaf(__int_as_float(e1.y), a1, acc);
        acc = fmaf(__int_as_float(e2.y), a2, acc);
        acc = fmaf(__int_as_float(e3.y), a3, acc);
    }
    for (; i < e; ++i) {
        int2 ed = edges[i];
        const float* p = (ed.x < split) ? srcA + (size_t)ed.x * 64 : srcB + (size_t)(ed.x - split) * 64;
        acc = fmaf(__int_as_float(ed.y), p[lane], acc);
    }
    out[(size_t)w * 64 + lane] = acc;
}

// ---------------- fused dense ----------------
__global__ __launch_bounds__(256, 1) void k_dense(const float* __restrict__ x_in,
                                                  const float* __restrict__ Wg,
                                                  const float* __restrict__ bg,
                                                  const float* __restrict__ Wm,
                                                  const float* __restrict__ bm,
                                                  float* __restrict__ out,
                                                  float* __restrict__ rnorm) {
    __shared__ __align__(16) float sWgT[4096];
    __shared__ __align__(16) float sWm[4096];
    __shared__ float sbg[64], sbm[64];
    int tid = threadIdx.x;
    for (int i = tid; i < 4096; i += 256) {
        int k = i >> 6, j = i & 63;
        sWgT[j * 64 + k] = Wg[i];
        sWm[i] = Wm[i];
    }
    if (tid < 64) {
        sbg[tid] = bg[tid];
        sbm[tid] = bm[tid];
    }
    __syncthreads();
    int r = blockIdx.x * 256 + tid;
    if (r >= N_CNT) return;

    float4 x4[16];
    const float4* xp = (const float4*)(x_in + (size_t)r * 64);
#pragma unroll
    for (int i = 0; i < 16; ++i) x4[i] = xp[i];

    float z[64];
#pragma unroll
    for (int j = 0; j < 64; ++j) z[j] = sbm[j];

    for (int j = 0; j < 64; ++j) {
        float acc = sbg[j];
#pragma unroll
        for (int k = 0; k < 16; ++k) {
            float4 w = *(const float4*)&sWgT[j * 64 + k * 4];
            acc = fmaf(x4[k].x, w.x, acc);
            acc = fmaf(x4[k].y, w.y, acc);
            acc = fmaf(x4[k].z, w.z, acc);
            acc = fmaf(x4[k].w, w.w, acc);
        }
        float y = (acc >= 0.f) ? acc : NEG_SLOPE * acc;
#pragma unroll
        for (int k = 0; k < 16; ++k) {
            float4 w = *(const float4*)&sWm[j * 64 + k * 4];
            z[k * 4 + 0] = fmaf(y, w.x, z[k * 4 + 0]);
            z[k * 4 + 1] = fmaf(y, w.y, z[k * 4 + 1]);
            z[k * 4 + 2] = fmaf(y, w.z, z[k * 4 + 2]);
            z[k * 4 + 3] = fmaf(y, w.w, z[k * 4 + 3]);
        }
    }
    float nrm2 = 0.f;
#pragma unroll
    for (int j = 0; j < 64; ++j) nrm2 = fmaf(z[j], z[j], nrm2);
    float nrm = sqrtf(nrm2);
    float rn = 1.f / fmaxf(nrm, 1e-12f);
    rnorm[r] = rn;
    float4* op = (float4*)(out + (size_t)r * 64);
#pragma unroll
    for (int i = 0; i < 16; ++i) {
        float4 t;
        t.x = z[i * 4 + 0];
        t.y = z[i * 4 + 1];
        t.z = z[i * 4 + 2];
        t.w = z[i * 4 + 3];
        op[i] = t;
    }
}

// ---------------- BPR scoring: grid-stride waves, 2 atomics/block ----------------
#define SCORE_BLOCKS 128
__global__ __launch_bounds__(256) void k_score(const int* __restrict__ user,
                                               const int* __restrict__ posi,
                                               const int* __restrict__ negi,
                                               const float* __restrict__ uemb,
                                               const float* __restrict__ iemb,
                                               const float* __restrict__ ego1,
                                               const float* __restrict__ rn1,
                                               const float* __restrict__ ego2,
                                               const float* __restrict__ rn2,
                                               float* __restrict__ out) {
    __shared__ float ssp[4], srg[4];
    int tid = threadIdx.x;
    int lane = tid & 63;
    int wv = tid >> 6;                       // wave in block (0..3)
    int gw = blockIdx.x * 4 + wv;            // global wave id
    const int NW = SCORE_BLOCKS * 4;

    float sp_acc = 0.f, rg_acc = 0.f;
    for (int w = gw; w < B_CNT; w += NW) {
        int iu = user[w], ip = posi[w], ineg = negi[w];
        size_t ru = (size_t)iu;
        size_t rp = (size_t)U_CNT + ip;
        size_t rn_ = (size_t)U_CNT + ineg;

        float u0 = uemb[(size_t)iu * 64 + lane];
        float p0 = iemb[(size_t)ip * 64 + lane];
        float n0 = iemb[(size_t)ineg * 64 + lane];
        float pos = u0 * p0;
        float neg = u0 * n0;
        float reg = u0 * u0 + p0 * p0 + n0 * n0;

        float a1 = rn1[ru], b1 = rn1[rp], c1 = rn1[rn_];
        float u1 = ego1[ru * 64 + lane] * a1;
        float p1 = ego1[rp * 64 + lane] * b1;
        float n1 = ego1[rn_ * 64 + lane] * c1;
        pos = fmaf(u1, p1, pos);
        neg = fmaf(u1, n1, neg);

        float a2 = rn2[ru], b2 = rn2[rp], c2 = rn2[rn_];
        float u2 = ego2[ru * 64 + lane] * a2;
        float p2 = ego2[rp * 64 + lane] * b2;
        float n2 = ego2[rn_ * 64 + lane] * c2;
        pos = fmaf(u2, p2, pos);
        neg = fmaf(u2, n2, neg);

#pragma unroll
        for (int off = 32; off; off >>= 1) {
            pos += __shfl_xor(pos, off);
            neg += __shfl_xor(neg, off);
            reg += __shfl_xor(reg, off);
        }
        float t = neg - pos;
        float sp = fmaxf(t, 0.f) + log1pf(expf(-fabsf(t)));
        sp_acc += sp;
        rg_acc += reg;
    }
    if (lane == 0) {
        ssp[wv] = sp_acc;
        srg[wv] = rg_acc;
    }
    __syncthreads();
    if (tid == 0) {
        float s = ssp[0] + ssp[1] + ssp[2] + ssp[3];
        float r = srg[0] + srg[1] + srg[2] + srg[3];
        atomicAdd(&out[0], s * (1.0f / B_CNT));
        atomicAdd(&out[1], r * (0.5f * REG_LAMBDA / B_CNT));
    }
}

// ---------------- launch ----------------

static inline size_t alignup(size_t x) { return (x + 255) & ~(size_t)255; }

extern "C" void kernel_launch(void* const* d_in, const int* in_sizes, int n_in,
                              void* d_out, int out_size, void* d_ws, size_t ws_size,
                              hipStream_t stream) {
    const int* user = (const int*)d_in[0];
    const int* posi = (const int*)d_in[1];
    const int* negi = (const int*)d_in[2];
    const int* rows = (const int*)d_in[3];
    const int* cols = (const int*)d_in[4];
    const float* vals = (const float*)d_in[5];
    const float* uemb = (const float*)d_in[6];
    const float* iemb = (const float*)d_in[7];
    const float* Wg0 = (const float*)d_in[8];
    const float* bg0 = (const float*)d_in[9];
    const float* Wm0 = (const float*)d_in[10];
    const float* bm0 = (const float*)d_in[11];
    const float* Wg1 = (const float*)d_in[12];
    const float* bg1 = (const float*)d_in[13];
    const float* Wm1 = (const float*)d_in[14];
    const float* bm1 = (const float*)d_in[15];
    const int E = in_sizes[3];
    float* out = (float*)d_out;

    char* p = (char*)d_ws;
    auto take = [&](size_t bytes) -> char* {
        char* q = p;
        p += alignup(bytes);
        return q;
    };
    int* rs = (int*)take((size_t)(N_CNT + 1) * 4);
    int* bcnt = (int*)take((size_t)NBK * 4 * 2);
    int* bfill = bcnt + NBK;
    int* bb = (int*)take((size_t)(NBK + 1) * 4);
    int2* edges = (int2*)take((size_t)E * 8);
    float* side = (float*)take((size_t)N_CNT * 64 * 4);
    float* ego1 = (float*)take((size_t)N_CNT * 64 * 4);
    float* ego2 = (float*)take((size_t)N_CNT * 64 * 4);
    float* rn1 = (float*)take((size_t)N_CNT * 4);
    float* rn2 = (float*)take((size_t)N_CNT * 4);

    hipMemsetAsync(out, 0, 2 * sizeof(float), stream);
    hipMemsetAsync(bcnt, 0, (size_t)NBK * 4 * 2, stream);

    k_bhist<<<256, 256, 0, stream>>>(rows, bcnt, E);
    k_bscan<<<1, 256, 0, stream>>>(bcnt, bb, NBK);
    k_bscatterA<<<256, 256, 0, stream>>>(rows, cols, vals, bb, bfill, edges, E);
    k_bfinal<<<NBK, 256, 0, stream>>>(edges, bb, rs, E);

    int sb = (N_CNT * 64 + 255) / 256;
    int db = (N_CNT + 255) / 256;

    k_spmm<<<sb, 256, 0, stream>>>(rs, edges, uemb, iemb, U_CNT, side);
    k_dense<<<db, 256, 0, stream>>>(side, Wg0, bg0, Wm0, bm0, ego1, rn1);
    k_spmm<<<sb, 256, 0, stream>>>(rs, edges, ego1, ego1, N_CNT, side);
    k_dense<<<db, 256, 0, stream>>>(side, Wg1, bg1, Wm1, bm1, ego2, rn2);

    k_score<<<SCORE_BLOCKS, 256, 0, stream>>>(user, posi, negi, uemb, iemb,
                                              ego1, rn1, ego2, rn2, out);
}

// Round 4
// 637.905 us; speedup vs baseline: 1.6438x; 1.0415x over previous
//
#include <hip/hip_runtime.h>
#include <math.h>

#define U_CNT 100000
#define I_CNT 50000
#define D_DIM 64
#define N_CNT 150000
#define B_CNT 8192
#define NEG_SLOPE 0.2f
#define REG_LAMBDA 1e-4f

#define RPB 128
#define NBK ((N_CNT + RPB - 1) / RPB)
#define CAP 4096

__device__ __forceinline__ float bf2f(unsigned short u) {
    return __uint_as_float((unsigned int)u << 16);
}
__device__ __forceinline__ unsigned short f2bf(float f) {
    unsigned int x = __float_as_uint(f);
    x += 0x7FFFu + ((x >> 16) & 1u);   // RNE
    return (unsigned short)(x >> 16);
}

// ---------------- bf16 conversion of concat(uemb, iemb) -> [N][64] ----------------
__global__ __launch_bounds__(256) void k_cvt(const float* __restrict__ uemb,
                                             const float* __restrict__ iemb,
                                             unsigned short* __restrict__ dst) {
    long long i = (long long)blockIdx.x * 256 + threadIdx.x;  // one thread = 8 elems
    long long base = i * 8;
    const long long TOT = (long long)N_CNT * 64;
    if (base >= TOT) return;
    const long long USZ = (long long)U_CNT * 64;
    const float* s = (base < USZ) ? uemb + base : iemb + (base - USZ);
    float4 a = *(const float4*)s;
    float4 b = *(const float4*)(s + 4);
    union { unsigned short us[8]; uint4 v; } o;
    o.us[0] = f2bf(a.x); o.us[1] = f2bf(a.y); o.us[2] = f2bf(a.z); o.us[3] = f2bf(a.w);
    o.us[4] = f2bf(b.x); o.us[5] = f2bf(b.y); o.us[6] = f2bf(b.z); o.us[7] = f2bf(b.w);
    *(uint4*)(dst + base) = o.v;
}

// ---------------- bucketed CSR build ----------------

__global__ __launch_bounds__(256) void k_bhist(const int* __restrict__ rows,
                                               int* __restrict__ bcnt, int E) {
    __shared__ int h[NBK];
    for (int i = threadIdx.x; i < NBK; i += 256) h[i] = 0;
    __syncthreads();
    int per = (E + gridDim.x - 1) / gridDim.x;
    int s = blockIdx.x * per, e = min(E, s + per);
    for (int i = s + threadIdx.x; i < e; i += 256) atomicAdd(&h[rows[i] >> 7], 1);
    __syncthreads();
    for (int i = threadIdx.x; i < NBK; i += 256) {
        int v = h[i];
        if (v) atomicAdd(&bcnt[i], v);
    }
}

__global__ void k_bscan(const int* __restrict__ bcnt, int* __restrict__ bb, int n) {
    __shared__ int lds[256];
    __shared__ int base;
    int tid = threadIdx.x;
    if (tid == 0) { base = 0; bb[0] = 0; }
    __syncthreads();
    for (int start = 0; start < n; start += 256) {
        int i = start + tid;
        int x = (i < n) ? bcnt[i] : 0;
        lds[tid] = x;
        __syncthreads();
        for (int off = 1; off < 256; off <<= 1) {
            int t = (tid >= off) ? lds[tid - off] : 0;
            __syncthreads();
            lds[tid] += t;
            __syncthreads();
        }
        if (i < n) bb[i + 1] = base + lds[tid];
        __syncthreads();
        if (tid == 0) base += lds[255];
        __syncthreads();
    }
}

__global__ __launch_bounds__(256) void k_bscatterA(const int* __restrict__ rows,
                                                   const int* __restrict__ cols,
                                                   const float* __restrict__ vals,
                                                   const int* __restrict__ bb,
                                                   int* __restrict__ bfill,
                                                   int2* __restrict__ edges, int E) {
    __shared__ int h[NBK];
    __shared__ int f[NBK];
    for (int i = threadIdx.x; i < NBK; i += 256) { h[i] = 0; f[i] = 0; }
    __syncthreads();
    int per = (E + gridDim.x - 1) / gridDim.x;
    int s = blockIdx.x * per, e = min(E, s + per);
    for (int i = s + threadIdx.x; i < e; i += 256) atomicAdd(&h[rows[i] >> 7], 1);
    __syncthreads();
    for (int i = threadIdx.x; i < NBK; i += 256) {
        int c = h[i];
        h[i] = c ? atomicAdd(&bfill[i], c) : 0;
    }
    __syncthreads();
    for (int i = s + threadIdx.x; i < e; i += 256) {
        int r = rows[i];
        int b = r >> 7, rl = r & 127;
        int pos = atomicAdd(&f[b], 1);
        int slot = bb[b] + h[b] + pos;
        edges[slot] = make_int2((rl << 18) | cols[i], __float_as_int(vals[i]));
    }
}

__global__ __launch_bounds__(256) void k_bfinal(int2* __restrict__ edges,
                                                const int* __restrict__ bb,
                                                int* __restrict__ rs, int E) {
    __shared__ int2 led[CAP];
    __shared__ int lcnt[RPB], lscan[RPB], lfill[RPB];
    int b = blockIdx.x;
    int s = bb[b], e = bb[b + 1];
    int nb = e - s;
    int tid = threadIdx.x;
    if (tid < RPB) { lcnt[tid] = 0; lfill[tid] = 0; }
    __syncthreads();
    for (int i = tid; i < nb; i += 256) {
        int2 ed = edges[s + i];
        if (i < CAP) led[i] = ed;
        atomicAdd(&lcnt[ed.x >> 18], 1);
    }
    __syncthreads();
    if (tid == 0) {
        int run = 0;
        for (int j = 0; j < RPB; ++j) { lscan[j] = run; run += lcnt[j]; }
    }
    __syncthreads();
    if (tid < RPB) {
        int row = b * RPB + tid;
        if (row < N_CNT) rs[row] = s + lscan[tid];
    }
    if (b == gridDim.x - 1 && tid == 0) rs[N_CNT] = E;
    int lim = min(nb, CAP);
    for (int i = tid; i < lim; i += 256) {
        int2 ed = led[i];
        int rl = ed.x >> 18;
        int pos = atomicAdd(&lfill[rl], 1);
        edges[s + lscan[rl] + pos] = make_int2(ed.x & 0x3FFFF, ed.y);
    }
    for (int base = CAP; base < nb; base += 256) {
        int i = base + tid;
        int2 ed;
        bool ok = (i < nb);
        if (ok) ed = edges[s + i];
        __syncthreads();
        if (ok) {
            int rl = ed.x >> 18;
            int pos = atomicAdd(&lfill[rl], 1);
            edges[s + lscan[rl] + pos] = make_int2(ed.x & 0x3FFFF, ed.y);
        }
        __syncthreads();
    }
}

// ---------------- SPMM: one wave per row, lane = dim, bf16 gathers ----------------
__global__ void k_spmm(const int* __restrict__ rs, const int2* __restrict__ edges,
                       const unsigned short* __restrict__ src,
                       unsigned short* __restrict__ out_bf) {
    int gid = blockIdx.x * blockDim.x + threadIdx.x;
    int w = gid >> 6;
    int lane = gid & 63;
    if (w >= N_CNT) return;
    int s = rs[w], e = rs[w + 1];
    float acc = 0.f;
    int i = s;
    for (; i + 4 <= e; i += 4) {
        int2 e0 = edges[i], e1 = edges[i + 1], e2 = edges[i + 2], e3 = edges[i + 3];
        float a0 = bf2f(src[e0.x * 64 + lane]);
        float a1 = bf2f(src[e1.x * 64 + lane]);
        float a2 = bf2f(src[e2.x * 64 + lane]);
        float a3 = bf2f(src[e3.x * 64 + lane]);
        acc = fmaf(__int_as_float(e0.y), a0, acc);
        acc = fmaf(__int_as_float(e1.y), a1, acc);
        acc = fmaf(__int_as_float(e2.y), a2, acc);
        acc = fmaf(__int_as_float(e3.y), a3, acc);
    }
    for (; i < e; ++i) {
        int2 ed = edges[i];
        acc = fmaf(__int_as_float(ed.y), bf2f(src[ed.x * 64 + lane]), acc);
    }
    out_bf[(size_t)w * 64 + lane] = f2bf(acc);
}

// ---------------- fused dense: leaky_relu(x@Wg+bg)@Wm+bm, row norm ----------------
// input x in bf16; outputs: f32 ego, 1/norm, optional bf16 ego copy.
template <int WRITE_BF>
__global__ __launch_bounds__(256, 1) void k_dense(const unsigned short* __restrict__ x_in,
                                                  const float* __restrict__ Wg,
                                                  const float* __restrict__ bg,
                                                  const float* __restrict__ Wm,
                                                  const float* __restrict__ bm,
                                                  float* __restrict__ out,
                                                  unsigned short* __restrict__ out_bf,
                                                  float* __restrict__ rnorm) {
    __shared__ __align__(16) float sWgT[4096];  // transposed: [j][k]
    __shared__ __align__(16) float sWm[4096];   // row-major:  [j][j2]
    __shared__ float sbg[64], sbm[64];
    int tid = threadIdx.x;
    for (int i = tid; i < 4096; i += 256) {
        int k = i >> 6, j = i & 63;
        sWgT[j * 64 + k] = Wg[i];
        sWm[i] = Wm[i];
    }
    if (tid < 64) {
        sbg[tid] = bg[tid];
        sbm[tid] = bm[tid];
    }
    __syncthreads();
    int r = blockIdx.x * 256 + tid;
    if (r >= N_CNT) return;

    float xr[64];
    const uint4* xp = (const uint4*)(x_in + (size_t)r * 64);
#pragma unroll
    for (int t = 0; t < 8; ++t) {
        uint4 q = xp[t];
        unsigned int u;
        u = q.x; xr[t * 8 + 0] = __uint_as_float(u << 16); xr[t * 8 + 1] = __uint_as_float(u & 0xFFFF0000u);
        u = q.y; xr[t * 8 + 2] = __uint_as_float(u << 16); xr[t * 8 + 3] = __uint_as_float(u & 0xFFFF0000u);
        u = q.z; xr[t * 8 + 4] = __uint_as_float(u << 16); xr[t * 8 + 5] = __uint_as_float(u & 0xFFFF0000u);
        u = q.w; xr[t * 8 + 6] = __uint_as_float(u << 16); xr[t * 8 + 7] = __uint_as_float(u & 0xFFFF0000u);
    }

    float z[64];
#pragma unroll
    for (int j = 0; j < 64; ++j) z[j] = sbm[j];

    for (int j = 0; j < 64; ++j) {
        float acc = sbg[j];
#pragma unroll
        for (int k = 0; k < 16; ++k) {
            float4 w = *(const float4*)&sWgT[j * 64 + k * 4];
            acc = fmaf(xr[k * 4 + 0], w.x, acc);
            acc = fmaf(xr[k * 4 + 1], w.y, acc);
            acc = fmaf(xr[k * 4 + 2], w.z, acc);
            acc = fmaf(xr[k * 4 + 3], w.w, acc);
        }
        float y = (acc >= 0.f) ? acc : NEG_SLOPE * acc;
#pragma unroll
        for (int k = 0; k < 16; ++k) {
            float4 w = *(const float4*)&sWm[j * 64 + k * 4];
            z[k * 4 + 0] = fmaf(y, w.x, z[k * 4 + 0]);
            z[k * 4 + 1] = fmaf(y, w.y, z[k * 4 + 1]);
            z[k * 4 + 2] = fmaf(y, w.z, z[k * 4 + 2]);
            z[k * 4 + 3] = fmaf(y, w.w, z[k * 4 + 3]);
        }
    }
    float nrm2 = 0.f;
#pragma unroll
    for (int j = 0; j < 64; ++j) nrm2 = fmaf(z[j], z[j], nrm2);
    float nrm = sqrtf(nrm2);
    float rn = 1.f / fmaxf(nrm, 1e-12f);
    rnorm[r] = rn;
    float4* op = (float4*)(out + (size_t)r * 64);
#pragma unroll
    for (int i = 0; i < 16; ++i) {
        float4 t;
        t.x = z[i * 4 + 0];
        t.y = z[i * 4 + 1];
        t.z = z[i * 4 + 2];
        t.w = z[i * 4 + 3];
        op[i] = t;
    }
    if (WRITE_BF) {
        uint4* bp = (uint4*)(out_bf + (size_t)r * 64);
#pragma unroll
        for (int t = 0; t < 8; ++t) {
            union { unsigned short us[8]; uint4 v; } o;
#pragma unroll
            for (int q = 0; q < 8; ++q) o.us[q] = f2bf(z[t * 8 + q]);
            bp[t] = o.v;
        }
    }
}

// ---------------- BPR scoring: grid-stride waves, 2 atomics/block ----------------
#define SCORE_BLOCKS 128
__global__ __launch_bounds__(256) void k_score(const int* __restrict__ user,
                                               const int* __restrict__ posi,
                                               const int* __restrict__ negi,
                                               const float* __restrict__ uemb,
                                               const float* __restrict__ iemb,
                                               const float* __restrict__ ego1,
                                               const float* __restrict__ rn1,
                                               const float* __restrict__ ego2,
                                               const float* __restrict__ rn2,
                                               float* __restrict__ out) {
    __shared__ float ssp[4], srg[4];
    int tid = threadIdx.x;
    int lane = tid & 63;
    int wv = tid >> 6;
    int gw = blockIdx.x * 4 + wv;
    const int NW = SCORE_BLOCKS * 4;

    float sp_acc = 0.f, rg_acc = 0.f;
    for (int w = gw; w < B_CNT; w += NW) {
        int iu = user[w], ip = posi[w], ineg = negi[w];
        size_t ru = (size_t)iu;
        size_t rp = (size_t)U_CNT + ip;
        size_t rn_ = (size_t)U_CNT + ineg;

        float u0 = uemb[(size_t)iu * 64 + lane];
        float p0 = iemb[(size_t)ip * 64 + lane];
        float n0 = iemb[(size_t)ineg * 64 + lane];
        float pos = u0 * p0;
        float neg = u0 * n0;
        float reg = u0 * u0 + p0 * p0 + n0 * n0;

        float a1 = rn1[ru], b1 = rn1[rp], c1 = rn1[rn_];
        float u1 = ego1[ru * 64 + lane] * a1;
        float p1 = ego1[rp * 64 + lane] * b1;
        float n1 = ego1[rn_ * 64 + lane] * c1;
        pos = fmaf(u1, p1, pos);
        neg = fmaf(u1, n1, neg);

        float a2 = rn2[ru], b2 = rn2[rp], c2 = rn2[rn_];
        float u2 = ego2[ru * 64 + lane] * a2;
        float p2 = ego2[rp * 64 + lane] * b2;
        float n2 = ego2[rn_ * 64 + lane] * c2;
        pos = fmaf(u2, p2, pos);
        neg = fmaf(u2, n2, neg);

#pragma unroll
        for (int off = 32; off; off >>= 1) {
            pos += __shfl_xor(pos, off);
            neg += __shfl_xor(neg, off);
            reg += __shfl_xor(reg, off);
        }
        float t = neg - pos;
        float sp = fmaxf(t, 0.f) + log1pf(expf(-fabsf(t)));
        sp_acc += sp;
        rg_acc += reg;
    }
    if (lane == 0) {
        ssp[wv] = sp_acc;
        srg[wv] = rg_acc;
    }
    __syncthreads();
    if (tid == 0) {
        float s = ssp[0] + ssp[1] + ssp[2] + ssp[3];
        float r = srg[0] + srg[1] + srg[2] + srg[3];
        atomicAdd(&out[0], s * (1.0f / B_CNT));
        atomicAdd(&out[1], r * (0.5f * REG_LAMBDA / B_CNT));
    }
}

// ---------------- launch ----------------

static inline size_t alignup(size_t x) { return (x + 255) & ~(size_t)255; }

extern "C" void kernel_launch(void* const* d_in, const int* in_sizes, int n_in,
                              void* d_out, int out_size, void* d_ws, size_t ws_size,
                              hipStream_t stream) {
    const int* user = (const int*)d_in[0];
    const int* posi = (const int*)d_in[1];
    const int* negi = (const int*)d_in[2];
    const int* rows = (const int*)d_in[3];
    const int* cols = (const int*)d_in[4];
    const float* vals = (const float*)d_in[5];
    const float* uemb = (const float*)d_in[6];
    const float* iemb = (const float*)d_in[7];
    const float* Wg0 = (const float*)d_in[8];
    const float* bg0 = (const float*)d_in[9];
    const float* Wm0 = (const float*)d_in[10];
    const float* bm0 = (const float*)d_in[11];
    const float* Wg1 = (const float*)d_in[12];
    const float* bg1 = (const float*)d_in[13];
    const float* Wm1 = (const float*)d_in[14];
    const float* bm1 = (const float*)d_in[15];
    const int E = in_sizes[3];
    float* out = (float*)d_out;

    char* p = (char*)d_ws;
    auto take = [&](size_t bytes) -> char* {
        char* q = p;
        p += alignup(bytes);
        return q;
    };
    int* rs = (int*)take((size_t)(N_CNT + 1) * 4);
    int* bcnt = (int*)take((size_t)NBK * 4 * 2);
    int* bfill = bcnt + NBK;
    int* bb = (int*)take((size_t)(NBK + 1) * 4);
    int2* edges = (int2*)take((size_t)E * 8);
    unsigned short* ego0_bf = (unsigned short*)take((size_t)N_CNT * 64 * 2);
    unsigned short* side_bf = (unsigned short*)take((size_t)N_CNT * 64 * 2);
    unsigned short* ego1_bf = (unsigned short*)take((size_t)N_CNT * 64 * 2);
    float* ego1 = (float*)take((size_t)N_CNT * 64 * 4);
    float* ego2 = (float*)take((size_t)N_CNT * 64 * 4);
    float* rn1 = (float*)take((size_t)N_CNT * 4);
    float* rn2 = (float*)take((size_t)N_CNT * 4);

    hipMemsetAsync(out, 0, 2 * sizeof(float), stream);
    hipMemsetAsync(bcnt, 0, (size_t)NBK * 4 * 2, stream);

    const long long TOT = (long long)N_CNT * 64;
    int cb = (int)((TOT / 8 + 255) / 256);
    k_cvt<<<cb, 256, 0, stream>>>(uemb, iemb, ego0_bf);

    k_bhist<<<256, 256, 0, stream>>>(rows, bcnt, E);
    k_bscan<<<1, 256, 0, stream>>>(bcnt, bb, NBK);
    k_bscatterA<<<256, 256, 0, stream>>>(rows, cols, vals, bb, bfill, edges, E);
    k_bfinal<<<NBK, 256, 0, stream>>>(edges, bb, rs, E);

    int sb = (N_CNT * 64 + 255) / 256;
    int db = (N_CNT + 255) / 256;

    k_spmm<<<sb, 256, 0, stream>>>(rs, edges, ego0_bf, side_bf);
    k_dense<1><<<db, 256, 0, stream>>>(side_bf, Wg0, bg0, Wm0, bm0, ego1, ego1_bf, rn1);
    k_spmm<<<sb, 256, 0, stream>>>(rs, edges, ego1_bf, side_bf);
    k_dense<0><<<db, 256, 0, stream>>>(side_bf, Wg1, bg1, Wm1, bm1, ego2, (unsigned short*)nullptr, rn2);

    k_score<<<SCORE_BLOCKS, 256, 0, stream>>>(user, posi, negi, uemb, iemb,
                                              ego1, rn1, ego2, rn2, out);
}